// Round 9
// baseline (530.910 us; speedup 1.0000x reference)
//
#include <hip/hip_runtime.h>
#include <hip/hip_bf16.h>
#include <hip/hip_fp16.h>

#define B_ 8
#define S_ 2048
#define D_ 512

typedef _Float16 f16x8 __attribute__((ext_vector_type(8)));
typedef _Float16 f16x4 __attribute__((ext_vector_type(4)));
typedef float f32x4 __attribute__((ext_vector_type(4)));

// async global->LDS, 16B per lane (HW: wave-uniform LDS base + lane*16)
__device__ __forceinline__ void gload16(const void* g, void* l) {
    __builtin_amdgcn_global_load_lds(
        (const __attribute__((address_space(1))) void*)g,
        (__attribute__((address_space(3))) void*)l, 16, 0, 0);
}

// ---------------------------------------------------------------------------
// Kernel 1: W (fp32 [k][n]) -> W^T (fp16 [n][k])
// ---------------------------------------------------------------------------
__global__ void wconv_kernel(const float* __restrict__ Wq,
                             const float* __restrict__ Wk,
                             const float* __restrict__ Wv,
                             _Float16* __restrict__ w_ws) {
    int idx = blockIdx.x * 256 + threadIdx.x;       // 0 .. 512*512-1
    int which = blockIdx.y;
    const float* W = (which == 0) ? Wq : (which == 1) ? Wk : Wv;
    int n = idx >> 9;
    int k = idx & 511;
    w_ws[(size_t)which * D_ * D_ + (size_t)n * D_ + k] = (_Float16)W[(size_t)k * D_ + n];
}

// ---------------------------------------------------------------------------
// Kernel 1b: X (fp32) -> fp16, coalesced stream.
// ---------------------------------------------------------------------------
__global__ void xconv_kernel(const float* __restrict__ Q,
                             const float* __restrict__ K,
                             const float* __restrict__ V,
                             _Float16* __restrict__ x16) {
    int which = blockIdx.y;
    const float* X = (which == 0) ? Q : (which == 1) ? K : V;
    _Float16* dst = x16 + (size_t)which * (16384ull * 512);
    size_t i0 = ((size_t)blockIdx.x * 256 + threadIdx.x) * 4;
    const size_t step = 2048ull * 256 * 4;   // 2,097,152 elements per sweep
#pragma unroll
    for (int it = 0; it < 4; it++) {
        size_t i = i0 + (size_t)it * step;
        float4 v = *(const float4*)(X + i);
        f16x4 h;
        h[0] = (_Float16)v.x; h[1] = (_Float16)v.y;
        h[2] = (_Float16)v.z; h[3] = (_Float16)v.w;
        *(f16x4*)(dst + i) = h;
    }
}

// ---------------------------------------------------------------------------
// Kernel 2: projection GEMM, fp16 A/B via global_load_lds, 2-phase pipeline
// (stage next K-tile before computing current; ONE barrier per K-step).
// Tile 128x128, BK=32. XCD remap: A-row panels partitioned per XCD.
// v output stored transposed v_ws[b][d][s].
// ---------------------------------------------------------------------------
__launch_bounds__(256, 4)
__global__ void proj_kernel(const _Float16* __restrict__ x16,
                            const _Float16* __restrict__ w_ws,
                            const float* __restrict__ bq,
                            const float* __restrict__ bk,
                            const float* __restrict__ bv,
                            _Float16* __restrict__ q_ws,
                            _Float16* __restrict__ k_ws,
                            _Float16* __restrict__ v_ws) {
    __shared__ __align__(16) _Float16 As[2][128 * 32];   // 8 KB each
    __shared__ __align__(16) _Float16 Bs[2][128 * 32];

    const int which = blockIdx.z;
    const _Float16* X = x16 + (size_t)which * (16384ull * 512);
    const float* bias = (which == 0) ? bq : (which == 1) ? bk : bv;
    const _Float16* Wt = w_ws + (size_t)which * D_ * D_;

    // XCD remap: hardware XCD = linear%8. Give each XCD a contiguous slab of
    // 16 Mb-panels; the 4 Nb-blocks of one panel run consecutively on it.
    const int linear = blockIdx.y * 4 + blockIdx.x;   // 0..511
    const int xcd = linear & 7;
    const int i = linear >> 3;                        // 0..63
    const int Mb = (xcd * 16 + (i >> 2)) * 128;
    const int Nb = (i & 3) * 128;

    const int t = threadIdx.x;
    const int w = t >> 6;
    const int l = t & 63;
    const int lr = l & 15;
    const int lk = (l >> 4) * 8;
    const int lq = (l >> 4) * 4;

#define PROJ_STAGE(buf, k0_)                                                   \
    do {                                                                       \
        int c = t;                                                             \
        _Pragma("unroll")                                                      \
        for (int r_ = 0; r_ < 2; r_++, c += 256) {                             \
            int row = c >> 2, p = c & 3;                                       \
            gload16(X + (size_t)(Mb + row) * D_ + (k0_) + ((p ^ (row & 3)) << 3), \
                    &As[buf][c * 8]);                                          \
        }                                                                      \
        c = t;                                                                 \
        _Pragma("unroll")                                                      \
        for (int r_ = 0; r_ < 2; r_++, c += 256) {                             \
            int col = c >> 2, p = c & 3;                                       \
            gload16(Wt + (size_t)(Nb + col) * D_ + (k0_) + ((p ^ (col & 3)) << 3), \
                    &Bs[buf][c * 8]);                                          \
        }                                                                      \
    } while (0)

    f32x4 acc[2][8] = {};
    PROJ_STAGE(0, 0);
    __syncthreads();

    int cur = 0;
    for (int k0 = 0; k0 < D_; k0 += 32) {
        if (k0 + 32 < D_) PROJ_STAGE(cur ^ 1, k0 + 32);

        const int s = lk >> 3;
        f16x8 a[2], b[8];
#pragma unroll
        for (int mi = 0; mi < 2; mi++) {
            int row = w * 32 + mi * 16 + lr;
            a[mi] = *(const f16x8*)&As[cur][row * 32 + ((s ^ (row & 3)) << 3)];
        }
#pragma unroll
        for (int ni = 0; ni < 8; ni++) {
            int col = ni * 16 + lr;
            b[ni] = *(const f16x8*)&Bs[cur][col * 32 + ((s ^ (col & 3)) << 3)];
        }
#pragma unroll
        for (int mi = 0; mi < 2; mi++)
#pragma unroll
            for (int ni = 0; ni < 8; ni++)
                acc[mi][ni] = __builtin_amdgcn_mfma_f32_16x16x32_f16(a[mi], b[ni], acc[mi][ni], 0, 0, 0);
        __syncthreads();   // drains staging vmcnt; protects cur-buffer reuse
        cur ^= 1;
    }

    // epilogue: + bias, cast fp16, store (v transposed)
#pragma unroll
    for (int ni = 0; ni < 8; ni++) {
        int col = Nb + ni * 16 + lr;
        float bn = bias[col];
#pragma unroll
        for (int mi = 0; mi < 2; mi++) {
#pragma unroll
            for (int j = 0; j < 4; j++) {
                int row = Mb + w * 32 + mi * 16 + lq + j;
                float vv = acc[mi][ni][j] + bn;
                if (which == 0) {
                    q_ws[(size_t)row * D_ + col] = (_Float16)vv;
                } else if (which == 1) {
                    k_ws[(size_t)row * D_ + col] = (_Float16)vv;
                } else {
                    int bb = row >> 11, s2 = row & 2047;
                    v_ws[((size_t)bb * D_ + col) * S_ + s2] = (_Float16)vv;
                }
            }
        }
    }
}

// ---------------------------------------------------------------------------
// Kernel 3: flash attention. QBLK=32, KVBLK=256, 512 thr = 8 waves.
// Q/K loads software-pipelined (2-step dbuf groups, ~16 loads in flight),
// V 1-group-ahead. Separate P_lds -> 2 barriers/tile. LDS ~50KB.
// ---------------------------------------------------------------------------
__launch_bounds__(512, 4)
__global__ void attn_kernel(const _Float16* __restrict__ q_ws,
                            const _Float16* __restrict__ k_ws,
                            const _Float16* __restrict__ v_ws,
                            float* __restrict__ out) {
    __shared__ __align__(16) float    S_lds[32][260];   // 33.25 KB
    __shared__ __align__(16) _Float16 P_lds[32][272];   // 17 KB
    __shared__ float m_lds[32];
    __shared__ float l_lds[32];
    __shared__ float alpha_lds[32];

    const int bid = blockIdx.x;
    const int b  = bid & 7;        // batch == XCD (round-robin dispatch)
    const int qb = (bid >> 3) * 32;

    const int t = threadIdx.x;
    const int w = t >> 6;          // wave 0..7
    const int l = t & 63;
    const int kc = w;              // kv-chunk (QK^T) / d-chunk (PV)
    const int lr = l & 15;
    const int lk = (l >> 4) * 8;
    const int lq = (l >> 4) * 4;

    const _Float16* qp = q_ws + (size_t)b * S_ * D_;
    const _Float16* kp = k_ws + (size_t)b * S_ * D_;
    const _Float16* vp = v_ws + (size_t)b * D_ * S_;

    // wave-invariant Q fragment row bases (L1/L2-hot, reread each tile)
    const _Float16* qrow0 = qp + (size_t)(qb + 0  + lr) * D_ + lk;
    const _Float16* qrow1 = qp + (size_t)(qb + 16 + lr) * D_ + lk;

    if (t < 32) { m_lds[t] = -INFINITY; l_lds[t] = 0.f; }

    f32x4 oacc[2][4] = {};
    __syncthreads();

#define QK_LOAD(QB, KB, g)                                                     \
    do {                                                                       \
        _Pragma("unroll")                                                      \
        for (int st = 0; st < 2; st++) {                                       \
            const int ds = (g) * 2 + st;                                       \
            QB[st][0] = *(const f16x8*)(qrow0 + ds * 32);                      \
            QB[st][1] = *(const f16x8*)(qrow1 + ds * 32);                      \
            _Pragma("unroll")                                                  \
            for (int ni = 0; ni < 2; ni++)                                     \
                KB[st][ni] = *(const f16x8*)(krow + (size_t)(ni * 16 + lr) * D_ + ds * 32 + lk); \
        }                                                                      \
    } while (0)

#define QK_MFMA(QB, KB)                                                        \
    do {                                                                       \
        _Pragma("unroll")                                                      \
        for (int st = 0; st < 2; st++)                                         \
            _Pragma("unroll")                                                  \
            for (int mi = 0; mi < 2; mi++)                                     \
                _Pragma("unroll")                                              \
                for (int ni = 0; ni < 2; ni++)                                 \
                    sacc[mi][ni] = __builtin_amdgcn_mfma_f32_16x16x32_f16(     \
                        QB[st][mi], KB[st][ni], sacc[mi][ni], 0, 0, 0);        \
    } while (0)

// NOTE: vrow must NOT include lr/lk — they are added here (round-5 bug fix).
#define PV_LOADV(VB, ks)                                                       \
    do {                                                                       \
        _Pragma("unroll")                                                      \
        for (int ni = 0; ni < 4; ni++)                                         \
            VB[ni] = *(const f16x8*)(vrow + (size_t)(ni * 16 + lr) * S_ + (ks) * 32 + lk); \
    } while (0)

    for (int kv0 = 0; kv0 < S_; kv0 += 256) {
        // ---- QK^T: wave kc computes S[0..32][kc*32..+32] over D=512
        f32x4 sacc[2][2] = {};
        const _Float16* krow = kp + (size_t)(kv0 + kc * 32) * D_;
        {
            f16x8 qA[2][2], kA[2][2], qB[2][2], kB[2][2];
            QK_LOAD(qA, kA, 0);
            QK_LOAD(qB, kB, 1);
#pragma unroll
            for (int g = 0; g < 8; g += 2) {
                QK_MFMA(qA, kA);
                if (g + 2 < 8) QK_LOAD(qA, kA, g + 2);
                QK_MFMA(qB, kB);
                if (g + 3 < 8) QK_LOAD(qB, kB, g + 3);
            }
        }
#pragma unroll
        for (int mi = 0; mi < 2; mi++)
#pragma unroll
            for (int ni = 0; ni < 2; ni++)
#pragma unroll
                for (int j = 0; j < 4; j++)
                    S_lds[mi * 16 + lq + j][kc * 32 + ni * 16 + lr] = sacc[mi][ni][j];
        __syncthreads();

        // ---- online softmax: 16 threads per row (32 rows x 256 cols)
        {
            const int r = t >> 4;
            const int cs = (t & 15) * 16;
            float sv[16];
#pragma unroll
            for (int c4 = 0; c4 < 4; c4++)
                *(float4*)&sv[c4 * 4] = *(const float4*)&S_lds[r][cs + c4 * 4];
            float mx = sv[0];
#pragma unroll
            for (int c = 1; c < 16; c++) mx = fmaxf(mx, sv[c]);
            mx = fmaxf(mx, __shfl_xor(mx, 1));
            mx = fmaxf(mx, __shfl_xor(mx, 2));
            mx = fmaxf(mx, __shfl_xor(mx, 4));
            mx = fmaxf(mx, __shfl_xor(mx, 8));
            float m_old = m_lds[r];
            float m_new = fmaxf(m_old, mx);
            float ps = 0.f;
            f16x8 p0, p1;
#pragma unroll
            for (int c = 0; c < 8; c++) {
                float p = __expf(sv[c] - m_new);
                ps += p;
                p0[c] = (_Float16)p;
            }
#pragma unroll
            for (int c = 0; c < 8; c++) {
                float p = __expf(sv[c + 8] - m_new);
                ps += p;
                p1[c] = (_Float16)p;
            }
            *(f16x8*)&P_lds[r][cs]     = p0;
            *(f16x8*)&P_lds[r][cs + 8] = p1;
            ps += __shfl_xor(ps, 1);
            ps += __shfl_xor(ps, 2);
            ps += __shfl_xor(ps, 4);
            ps += __shfl_xor(ps, 8);
            if ((t & 15) == 0) {
                float al = __expf(m_old - m_new);
                alpha_lds[r] = al;
                l_lds[r] = l_lds[r] * al + ps;
                m_lds[r] = m_new;
            }
        }
        __syncthreads();

        // ---- rescale O, then PV: wave kc owns d-cols kc*64..+64
#pragma unroll
        for (int mi = 0; mi < 2; mi++)
#pragma unroll
            for (int j = 0; j < 4; j++) {
                float al = alpha_lds[mi * 16 + lq + j];
#pragma unroll
                for (int ni = 0; ni < 4; ni++) oacc[mi][ni][j] *= al;
            }

        {
            const _Float16* vrow = vp + (size_t)(kc * 64) * S_ + kv0;   // FIXED
            f16x8 vA[4], vB[4];
            PV_LOADV(vA, 0);
            PV_LOADV(vB, 1);
#pragma unroll
            for (int ks = 0; ks < 8; ks += 2) {
                f16x8 pa[2];
#pragma unroll
                for (int mi = 0; mi < 2; mi++)
                    pa[mi] = *(const f16x8*)&P_lds[mi * 16 + lr][ks * 32 + lk];
#pragma unroll
                for (int mi = 0; mi < 2; mi++)
#pragma unroll
                    for (int ni = 0; ni < 4; ni++)
                        oacc[mi][ni] = __builtin_amdgcn_mfma_f32_16x16x32_f16(pa[mi], vA[ni], oacc[mi][ni], 0, 0, 0);
                if (ks + 2 < 8) PV_LOADV(vA, ks + 2);
#pragma unroll
                for (int mi = 0; mi < 2; mi++)
                    pa[mi] = *(const f16x8*)&P_lds[mi * 16 + lr][(ks + 1) * 32 + lk];
#pragma unroll
                for (int mi = 0; mi < 2; mi++)
#pragma unroll
                    for (int ni = 0; ni < 4; ni++)
                        oacc[mi][ni] = __builtin_amdgcn_mfma_f32_16x16x32_f16(pa[mi], vB[ni], oacc[mi][ni], 0, 0, 0);
                if (ks + 3 < 8) PV_LOADV(vB, ks + 3);
            }
        }
        // no barrier: PV's P-reads vs next softmax's P-writes are ordered by
        // the post-QK^T barrier of the next tile; S/P buffers are disjoint.
    }

    // ---- normalize and store fp32 output
#pragma unroll
    for (int mi = 0; mi < 2; mi++)
#pragma unroll
        for (int j = 0; j < 4; j++) {
            int row = mi * 16 + lq + j;
            float rl = 1.f / l_lds[row];
#pragma unroll
            for (int ni = 0; ni < 4; ni++) {
                int col = kc * 64 + ni * 16 + lr;
                out[((size_t)b * S_ + qb + row) * D_ + col] = oacc[mi][ni][j] * rl;
            }
        }
}

// ---------------------------------------------------------------------------
extern "C" void kernel_launch(void* const* d_in, const int* in_sizes, int n_in,
                              void* d_out, int out_size, void* d_ws, size_t ws_size,
                              hipStream_t stream) {
    const float* Q  = (const float*)d_in[0];
    const float* K  = (const float*)d_in[1];
    const float* V  = (const float*)d_in[2];
    const float* Wq = (const float*)d_in[3];
    const float* bq = (const float*)d_in[4];
    const float* Wk = (const float*)d_in[5];
    const float* bk = (const float*)d_in[6];
    const float* Wv = (const float*)d_in[7];
    const float* bv = (const float*)d_in[8];
    float* out = (float*)d_out;

    char* ws = (char*)d_ws;
    _Float16* w_ws = (_Float16*)ws;                                   // 3*512*512
    _Float16* x16  = (_Float16*)(ws + 3ull * 512 * 512 * 2);          // 3*[16384][512]
    _Float16* q_ws = x16 + 3ull * 16384 * 512;                        // [8][2048][512]
    _Float16* k_ws = q_ws + 8ull * 2048 * 512;                        // [8][2048][512]
    _Float16* v_ws = k_ws + 8ull * 2048 * 512;                        // [8][512][2048] (transposed)

    wconv_kernel<<<dim3(1024, 3), 256, 0, stream>>>(Wq, Wk, Wv, w_ws);
    xconv_kernel<<<dim3(2048, 3), 256, 0, stream>>>(Q, K, V, x16);
    proj_kernel<<<dim3(4, 128, 3), 256, 0, stream>>>(x16, w_ws, bq, bk, bv, q_ws, k_ws, v_ws);
    attn_kernel<<<dim3(512), 512, 0, stream>>>(q_ws, k_ws, v_ws, out);
}